// Round 4
// baseline (2718.082 us; speedup 1.0000x reference)
//
#include <hip/hip_runtime.h>
#include <hip/hip_cooperative_groups.h>
#include <math.h>

namespace cg = cooperative_groups;

#define T_ 256
#define B_ 256
#define I_ 256
#define H_ 512
#define NB 8          // batch groups (independent recurrent chains)
#define NH 32         // h-group WGs per batch group
#define BG 32         // batches per group
#define NTH 512

typedef __attribute__((ext_vector_type(8))) short short8;
typedef __attribute__((ext_vector_type(4))) float f32x4;
typedef __attribute__((ext_vector_type(4))) unsigned int uint4v;

__device__ __forceinline__ float sig_(float v){ return 1.0f/(1.0f+__expf(-v)); }
__device__ __forceinline__ float tanh_(float v){ float e=__expf(2.f*v); return 1.f-2.f/(e+1.f); }
__device__ __forceinline__ short f2bf(float f){            // fp32 -> bf16 RTNE
  unsigned u = __float_as_uint(f);
  return (short)((u + 0x7fffu + ((u>>16)&1u)) >> 16);
}

__global__ __launch_bounds__(NTH)
void qlstm_kernel(
    const float* __restrict__ x,
    const float* __restrict__ Wf_l, const float* __restrict__ bf_l,
    const float* __restrict__ Wf_p, const float* __restrict__ bf_p,
    const float* __restrict__ Wf_r,
    const float* __restrict__ Wi_l, const float* __restrict__ bi_l,
    const float* __restrict__ Wi_p, const float* __restrict__ bi_p,
    const float* __restrict__ Wi_r,
    const float* __restrict__ Wg_l, const float* __restrict__ bg_l,
    const float* __restrict__ Wg_p, const float* __restrict__ bg_p,
    const float* __restrict__ Wg_r,
    const float* __restrict__ Wo_l, const float* __restrict__ bo_l,
    const float* __restrict__ Wo_p, const float* __restrict__ bo_p,
    const float* __restrict__ Wo_r,
    float* __restrict__ out,
    char* __restrict__ wsb)
{
  __shared__ char hxT[32*1024];         // [32 b][512 k] bf16, XOR-swizzled rows

  float* sx   = (float*)wsb;                         // [T][4][B] fp32, 1 MiB
  char*  hxg  = wsb + (1u<<20);                      // 2 x [BG*? ][H] bf16 per group, 512 KiB total
  char*  seqb = wsb + (1u<<20) + (512u<<10);         // seq words: [(bgp*8+w)*NH + nh], 8 KiB

  const int tid  = threadIdx.x;
  const int wgid = blockIdx.x;
  const int bgp  = wgid & 7;            // batch group
  const int nh   = wgid >> 3;           // h group 0..31
  const int wave = tid >> 6;
  const int l    = tid & 63;
  const int l15  = l & 15;
  const int q4   = l >> 4;
  const int n    = wave >> 2;           // batch half (0/1)
  const int wq   = wave & 3;            // h quad within the WG's 16 h

  // ---------------- init (once per launch) ----------------
  // sx[t][g][b] = x[t,b,:] . Wl_g[0,:I] + bl_g[0]
  for (int idx = tid; idx < 8*4*BG; idx += NTH) {
    int g   = idx >> 8;
    int rem = idx & 255;
    int tt  = rem >> 5;
    int b   = rem & 31;
    int t   = nh*8 + tt;
    int bglob = bgp*BG + b;
    const float* wl = (g==0)?Wf_l:(g==1)?Wi_l:(g==2)?Wg_l:Wo_l;
    const float* bl = (g==0)?bf_l:(g==1)?bi_l:(g==2)?bg_l:bo_l;
    const float* xr = x + ((size_t)t*B_ + bglob)*I_;
    float a = 0.f;
    #pragma unroll 8
    for (int i2 = 0; i2 < I_; i2 += 4) {
      float4 v = *(const float4*)(xr + i2);
      a += v.x*wl[i2] + v.y*wl[i2+1] + v.z*wl[i2+2] + v.w*wl[i2+3];
    }
    sx[((size_t)t*4 + g)*B_ + bglob] = a + bl[0];
  }
  // zero this WG's 8 seq slots (one per wave), write-through to LLC
  if (tid < 8) {
    unsigned long long sa =
      (unsigned long long)(seqb + (((size_t)bgp*8 + tid)*NH + nh)*4);
    unsigned z = 0;
    asm volatile("global_store_dword %0, %1, off sc0 sc1" :: "v"(sa), "v"(z) : "memory");
  }

  // A-fragments, gate-interleaved rows: row r -> (h = nh*16 + wq*4 + (r>>2), gate = r&3)
  // q-tile rows replicated: row r -> gate r&3 (all 4 q-dots reach every lane)
  short8 afrag[16];
  short8 afragq[16];
  {
    const int g  = l15 & 3;
    const float* wr = (g==0)?Wf_r:(g==1)?Wi_r:(g==2)?Wg_r:Wo_r;
    const float* wl = (g==0)?Wf_l:(g==1)?Wi_l:(g==2)?Wg_l:Wo_l;
    const int hA = nh*16 + wq*4 + (l15>>2);
    #pragma unroll
    for (int kk = 0; kk < 16; ++kk) {
      const float* srcA = wr + (size_t)hA*H_ + kk*32 + q4*8;
      const float* srcQ = wl + I_ + kk*32 + q4*8;
      short8 pa, pq;
      #pragma unroll
      for (int j = 0; j < 8; ++j) { pa[j] = f2bf(srcA[j]); pq[j] = f2bf(srcQ[j]); }
      afrag[kk]  = pa;
      afragq[kk] = pq;
    }
  }

  // lane-local epilogue ownership: b = bgp*32 + n*16 + l15, h = nh*16 + wq*4 + q4
  const int h_ep = nh*16 + wq*4 + q4;
  const int b_ep = bgp*BG + n*16 + l15;
  const float wfp = Wf_p[h_ep], bfp = bf_p[h_ep];
  const float wip = Wi_p[h_ep], bip = bi_p[h_ep];
  const float wgp = Wg_p[h_ep], bgw = bg_p[h_ep];
  const float wop = Wo_p[h_ep], bop = bo_p[h_ep];
  float cxr = 0.f;

  cg::grid_group grid = cg::this_grid();
  grid.sync();                          // publishes sx + seq zeroing device-wide

  const int bb   = n*16 + l15;
  const int brow = bb * 1024;
  const int bsw  = (bb & 7) << 4;
  const int bq16 = q4 * 16;

  for (int t = 0; t < T_; ++t) {
    // sx prefetch (L2-cached plain loads, consumed in epilogue)
    const float sx0 = sx[((size_t)t*4+0)*B_ + b_ep];
    const float sx1 = sx[((size_t)t*4+1)*B_ + b_ep];
    const float sx2 = sx[((size_t)t*4+2)*B_ + b_ep];
    const float sx3 = sx[((size_t)t*4+3)*B_ + b_ep];

    // ---- [A] stage hx: LLC (sc0 sc1) -> LDS swizzled; double-buffered by parity ----
    if (t == 0) {
      #pragma unroll
      for (int i = 0; i < 4; ++i)
        *(f32x4*)(hxT + ((wave*4+i)*1024 + 16*l)) = (f32x4){0.f,0.f,0.f,0.f};
    } else {
      uint4v v0, v1, v2, v3;
      unsigned long long base =
        (unsigned long long)(hxg + ((size_t)(t&1))*262144
                             + (((size_t)(bgp*BG + wave*4)) << 10) + 16*l);
      asm volatile("global_load_dwordx4 %0, %1, off sc0 sc1"             : "=v"(v0) : "v"(base) : "memory");
      asm volatile("global_load_dwordx4 %0, %1, off offset:1024 sc0 sc1" : "=v"(v1) : "v"(base) : "memory");
      asm volatile("global_load_dwordx4 %0, %1, off offset:2048 sc0 sc1" : "=v"(v2) : "v"(base) : "memory");
      asm volatile("global_load_dwordx4 %0, %1, off offset:3072 sc0 sc1" : "=v"(v3) : "v"(base) : "memory");
      asm volatile("s_waitcnt vmcnt(0)" ::: "memory");
      const int r0w = wave*4;
      *(uint4v*)(hxT + ((r0w  )*1024 + ((16*l) ^ (((r0w  )&7)<<4)))) = v0;
      *(uint4v*)(hxT + ((r0w+1)*1024 + ((16*l) ^ (((r0w+1)&7)<<4)))) = v1;
      *(uint4v*)(hxT + ((r0w+2)*1024 + ((16*l) ^ (((r0w+2)&7)<<4)))) = v2;
      *(uint4v*)(hxT + ((r0w+3)*1024 + ((16*l) ^ (((r0w+3)&7)<<4)))) = v3;
    }
    __syncthreads();                                        // S1: tile ready

    // ---- [B] MFMA K-loop: main (gate-interleaved) + q (replicated) ----
    f32x4 acc  = {0.f,0.f,0.f,0.f};
    f32x4 accq = {0.f,0.f,0.f,0.f};
    #pragma unroll
    for (int kk = 0; kk < 16; ++kk) {
      short8 bf = *(const short8*)(hxT + brow + ((kk*64 + bq16) ^ bsw));
      acc  = __builtin_amdgcn_mfma_f32_16x16x32_bf16(afrag[kk],  bf, acc,  0, 0, 0);
      accq = __builtin_amdgcn_mfma_f32_16x16x32_bf16(afragq[kk], bf, accq, 0, 0, 0);
    }
    // acc[r] = gate r residual for (b_ep, h_ep); accq[r] = hx . Wlh_r for b_ep

    // ---- [C] epilogue: fully lane-local ----
    float q0 = __cosf(sx0 + accq[0]);
    float q1 = __cosf(sx1 + accq[1]);
    float q2 = __cosf(sx2 + accq[2]);
    float q3 = __cosf(sx3 + accq[3]);
    float fv = sig_ (q0*wfp + bfp) + acc[0];
    float iv = sig_ (q1*wip + bip) + acc[1];
    float gv = tanh_(q2*wgp + bgw) + acc[2];
    float ov = sig_ (q3*wop + bop) + acc[3];
    cxr = fv*cxr + iv*gv;
    float hnew = ov * tanh_(cxr);
    out[((size_t)t*B_ + b_ep)*H_ + h_ep] = hnew;            // ys (cached store)

    if (t < T_-1) {
      // ---- [D] publish hx (2B write-through), drain, bump seq, poll, join ----
      unsigned hv = (unsigned)(unsigned short)f2bf(hnew);
      unsigned long long ha =
        (unsigned long long)(hxg + ((size_t)((t+1)&1))*262144
                             + ((size_t)b_ep*1024) + h_ep*2);
      asm volatile("global_store_short %0, %1, off sc0 sc1" :: "v"(ha), "v"(hv) : "memory");
      asm volatile("s_waitcnt vmcnt(0)" ::: "memory");      // wave-local drain (hx + ys)
      if (l == 0) {
        unsigned long long sa =
          (unsigned long long)(seqb + (((size_t)bgp*8 + wave)*NH + nh)*4);
        unsigned sv = (unsigned)(t+1);
        asm volatile("global_store_dword %0, %1, off sc0 sc1" :: "v"(sa), "v"(sv) : "memory");
      }
      {
        unsigned long long fa =
          (unsigned long long)(seqb + (((size_t)bgp*8 + wave)*NH + (l & 31))*4);
        unsigned v;
        do {
          asm volatile("global_load_dword %0, %1, off sc0 sc1\n\ts_waitcnt vmcnt(0)"
                       : "=v"(v) : "v"(fa) : "memory");
        } while (v < (unsigned)(t+1));
      }
      __syncthreads();                  // S2: all 8 wave-slices confirmed -> hxT reusable
    } else {
      out[(size_t)T_*B_*H_ + (size_t)b_ep*H_ + h_ep] = hnew;
      out[(size_t)T_*B_*H_ + (size_t)B_*H_ + (size_t)b_ep*H_ + h_ep] = cxr;
    }
  }
}

extern "C" void kernel_launch(void* const* d_in, const int* in_sizes, int n_in,
                              void* d_out, int out_size, void* d_ws, size_t ws_size,
                              hipStream_t stream) {
  const float* x    = (const float*)d_in[0];
  const float* Wf_l = (const float*)d_in[1];  const float* bf_l = (const float*)d_in[2];
  const float* Wf_p = (const float*)d_in[3];  const float* bf_p = (const float*)d_in[4];
  const float* Wf_r = (const float*)d_in[5];
  const float* Wi_l = (const float*)d_in[6];  const float* bi_l = (const float*)d_in[7];
  const float* Wi_p = (const float*)d_in[8];  const float* bi_p = (const float*)d_in[9];
  const float* Wi_r = (const float*)d_in[10];
  const float* Wg_l = (const float*)d_in[11]; const float* bg_l = (const float*)d_in[12];
  const float* Wg_p = (const float*)d_in[13]; const float* bg_p = (const float*)d_in[14];
  const float* Wg_r = (const float*)d_in[15];
  const float* Wo_l = (const float*)d_in[16]; const float* bo_l = (const float*)d_in[17];
  const float* Wo_p = (const float*)d_in[18]; const float* bo_p = (const float*)d_in[19];
  const float* Wo_r = (const float*)d_in[20];
  float* out = (float*)d_out;
  char*  wsb = (char*)d_ws;

  void* args[] = { &x,
                   &Wf_l, &bf_l, &Wf_p, &bf_p, &Wf_r,
                   &Wi_l, &bi_l, &Wi_p, &bi_p, &Wi_r,
                   &Wg_l, &bg_l, &Wg_p, &bg_p, &Wg_r,
                   &Wo_l, &bo_l, &Wo_p, &bo_p, &Wo_r,
                   &out, &wsb };
  hipLaunchCooperativeKernel((void*)qlstm_kernel, dim3(NB*NH), dim3(NTH),
                             args, 0, stream);
}

// Round 5
// 1551.822 us; speedup vs baseline: 1.7515x; 1.7515x over previous
//
#include <hip/hip_runtime.h>
#include <hip/hip_cooperative_groups.h>
#include <math.h>

namespace cg = cooperative_groups;

#define T_ 256
#define B_ 256
#define I_ 256
#define H_ 512
#define NB 8          // batch groups (independent recurrent chains)
#define NH 32         // h-group WGs per batch group
#define BG 32         // batches per group
#define NTH 512

typedef __attribute__((ext_vector_type(8))) short short8;
typedef __attribute__((ext_vector_type(4))) float f32x4;
typedef __attribute__((ext_vector_type(4))) unsigned int uint4v;

__device__ __forceinline__ float sig_(float v){ return 1.0f/(1.0f+__expf(-v)); }
__device__ __forceinline__ float tanh_(float v){ float e=__expf(2.f*v); return 1.f-2.f/(e+1.f); }
__device__ __forceinline__ unsigned f2bfu(float f){        // fp32 -> bf16 RTNE (as u32)
  unsigned u = __float_as_uint(f);
  return (u + 0x7fffu + ((u>>16)&1u)) >> 16;
}
__device__ __forceinline__ short f2bf(float f){ return (short)f2bfu(f); }

__global__ __launch_bounds__(NTH)
void qlstm_kernel(
    const float* __restrict__ x,
    const float* __restrict__ Wf_l, const float* __restrict__ bf_l,
    const float* __restrict__ Wf_p, const float* __restrict__ bf_p,
    const float* __restrict__ Wf_r,
    const float* __restrict__ Wi_l, const float* __restrict__ bi_l,
    const float* __restrict__ Wi_p, const float* __restrict__ bi_p,
    const float* __restrict__ Wi_r,
    const float* __restrict__ Wg_l, const float* __restrict__ bg_l,
    const float* __restrict__ Wg_p, const float* __restrict__ bg_p,
    const float* __restrict__ Wg_r,
    const float* __restrict__ Wo_l, const float* __restrict__ bo_l,
    const float* __restrict__ Wo_p, const float* __restrict__ bo_p,
    const float* __restrict__ Wo_r,
    float* __restrict__ out,
    char* __restrict__ wsb)
{
  __shared__ char  hxT[32*1024];        // [32 b][512 k] bf16, XOR-swizzled rows
  __shared__ float hxe[32*17];          // [b][h(+pad)] fp32 transpose tile

  float* sx   = (float*)wsb;                         // [T][4][B] fp32, 1 MiB
  char*  hxg  = wsb + (1u<<20);                      // 2 x [B][H] bf16 (parity dbuf), 512 KiB
  char*  seqb = wsb + (1u<<20) + (512u<<10);         // seq dwords: [(bgp*8+wave)*32 + nh], 8 KiB

  const int tid  = threadIdx.x;
  const int wgid = blockIdx.x;
  const int bgp  = wgid & 7;            // batch group
  const int nh   = wgid >> 3;           // h group 0..31
  const int wave = tid >> 6;
  const int l    = tid & 63;
  const int l15  = l & 15;
  const int q4   = l >> 4;
  const int n    = wave >> 2;           // batch half (0/1)
  const int wq   = wave & 3;            // h quad within the WG's 16 h

  // ---------------- init (once per launch) ----------------
  for (int idx = tid; idx < 8*4*BG; idx += NTH) {
    int g   = idx >> 8;
    int rem = idx & 255;
    int tt  = rem >> 5;
    int b   = rem & 31;
    int t   = nh*8 + tt;
    int bglob = bgp*BG + b;
    const float* wl = (g==0)?Wf_l:(g==1)?Wi_l:(g==2)?Wg_l:Wo_l;
    const float* bl = (g==0)?bf_l:(g==1)?bi_l:(g==2)?bg_l:bo_l;
    const float* xr = x + ((size_t)t*B_ + bglob)*I_;
    float a = 0.f;
    #pragma unroll 8
    for (int i2 = 0; i2 < I_; i2 += 4) {
      float4 v = *(const float4*)(xr + i2);
      a += v.x*wl[i2] + v.y*wl[i2+1] + v.z*wl[i2+2] + v.w*wl[i2+3];
    }
    sx[((size_t)t*4 + g)*B_ + bglob] = a + bl[0];
  }
  // zero this WG's 8 seq slots (one per wave), write-through to LLC (replay-safe)
  if (tid < 8) {
    unsigned long long sa =
      (unsigned long long)(seqb + (((size_t)bgp*8 + tid)*NH + nh)*4);
    unsigned z = 0;
    asm volatile("global_store_dword %0, %1, off sc0 sc1" :: "v"(sa), "v"(z) : "memory");
  }

  // A-fragments, gate-interleaved rows: tile row r -> (hloc = r>>2, gate = r&3)
  // q-tile rows replicated: row r -> gate r&3 (all 4 q-dots reach every lane)
  short8 afrag[16];
  short8 afragq[16];
  {
    const int g  = l15 & 3;
    const float* wr = (g==0)?Wf_r:(g==1)?Wi_r:(g==2)?Wg_r:Wo_r;
    const float* wl = (g==0)?Wf_l:(g==1)?Wi_l:(g==2)?Wg_l:Wo_l;
    const int hA = nh*16 + wq*4 + (l15>>2);
    #pragma unroll
    for (int kk = 0; kk < 16; ++kk) {
      const float* srcA = wr + (size_t)hA*H_ + kk*32 + q4*8;
      const float* srcQ = wl + I_ + kk*32 + q4*8;
      short8 pa, pq;
      #pragma unroll
      for (int j = 0; j < 8; ++j) { pa[j] = f2bf(srcA[j]); pq[j] = f2bf(srcQ[j]); }
      afrag[kk]  = pa;
      afragq[kk] = pq;
    }
  }

  // lane-local epilogue ownership: b = bgp*32 + n*16 + l15, h = nh*16 + wq*4 + q4
  const int h_ep = nh*16 + wq*4 + q4;
  const int b_ep = bgp*BG + n*16 + l15;
  const int eloc = n*16 + l15;          // local b 0..31
  const float wfp = Wf_p[h_ep], bfp = bf_p[h_ep];
  const float wip = Wi_p[h_ep], bip = bi_p[h_ep];
  const float wgp = Wg_p[h_ep], bgw = bg_p[h_ep];
  const float wop = Wo_p[h_ep], bop = bo_p[h_ep];
  float cxr = 0.f;

  // coalesced-output ownership (transpose side): eb = tid>>4, hl = tid&15
  const int hl = tid & 15;
  const int eb = tid >> 4;
  const int h_out = nh*16 + hl;
  const int b_out = bgp*BG + eb;

  cg::grid_group grid = cg::this_grid();
  grid.sync();                          // publishes sx + seq zeroing device-wide

  const int brow = eloc * 1024;
  const int bsw  = (eloc & 7) << 4;
  const int bq16 = q4 * 16;

  for (int t = 0; t < T_; ++t) {
    // sx prefetch (cached loads, consumed in epilogue)
    const float sx0 = sx[((size_t)t*4+0)*B_ + b_ep];
    const float sx1 = sx[((size_t)t*4+1)*B_ + b_ep];
    const float sx2 = sx[((size_t)t*4+2)*B_ + b_ep];
    const float sx3 = sx[((size_t)t*4+3)*B_ + b_ep];

    // ---- [A] stage hx: LLC (sc0 sc1) -> LDS swizzled; parity double-buffer ----
    if (t == 0) {
      #pragma unroll
      for (int i = 0; i < 4; ++i)
        *(f32x4*)(hxT + ((wave*4+i)*1024 + 16*l)) = (f32x4){0.f,0.f,0.f,0.f};
    } else {
      uint4v v0, v1, v2, v3;
      unsigned long long base =
        (unsigned long long)(hxg + ((size_t)(t&1))*262144
                             + (((size_t)(bgp*BG + wave*4)) << 10) + 16*l);
      asm volatile("global_load_dwordx4 %0, %1, off sc0 sc1"             : "=v"(v0) : "v"(base) : "memory");
      asm volatile("global_load_dwordx4 %0, %1, off offset:1024 sc0 sc1" : "=v"(v1) : "v"(base) : "memory");
      asm volatile("global_load_dwordx4 %0, %1, off offset:2048 sc0 sc1" : "=v"(v2) : "v"(base) : "memory");
      asm volatile("global_load_dwordx4 %0, %1, off offset:3072 sc0 sc1" : "=v"(v3) : "v"(base) : "memory");
      asm volatile("s_waitcnt vmcnt(0)" ::: "memory");
      const int r0w = wave*4;
      *(uint4v*)(hxT + ((r0w  )*1024 + ((16*l) ^ (((r0w  )&7)<<4)))) = v0;
      *(uint4v*)(hxT + ((r0w+1)*1024 + ((16*l) ^ (((r0w+1)&7)<<4)))) = v1;
      *(uint4v*)(hxT + ((r0w+2)*1024 + ((16*l) ^ (((r0w+2)&7)<<4)))) = v2;
      *(uint4v*)(hxT + ((r0w+3)*1024 + ((16*l) ^ (((r0w+3)&7)<<4)))) = v3;
    }
    __syncthreads();                                        // S1: tile ready

    // ---- [B] MFMA K-loop: main (gate-interleaved) + q (replicated) ----
    f32x4 acc  = {0.f,0.f,0.f,0.f};
    f32x4 accq = {0.f,0.f,0.f,0.f};
    #pragma unroll
    for (int kk = 0; kk < 16; ++kk) {
      short8 bf = *(const short8*)(hxT + brow + ((kk*64 + bq16) ^ bsw));
      acc  = __builtin_amdgcn_mfma_f32_16x16x32_bf16(afrag[kk],  bf, acc,  0, 0, 0);
      accq = __builtin_amdgcn_mfma_f32_16x16x32_bf16(afragq[kk], bf, accq, 0, 0, 0);
    }

    // ---- [C] epilogue: lane-local gates -> hnew -> transpose tile ----
    {
      float q0 = __cosf(sx0 + accq[0]);
      float q1 = __cosf(sx1 + accq[1]);
      float q2 = __cosf(sx2 + accq[2]);
      float q3 = __cosf(sx3 + accq[3]);
      float fv = sig_ (q0*wfp + bfp) + acc[0];
      float iv = sig_ (q1*wip + bip) + acc[1];
      float gv = tanh_(q2*wgp + bgw) + acc[2];
      float ov = sig_ (q3*wop + bop) + acc[3];
      cxr = fv*cxr + iv*gv;
      float hnew = ov * tanh_(cxr);
      hxe[eloc*17 + wq*4 + q4] = hnew;
    }
    __syncthreads();                                        // S3: hxe ready

    if (t < T_-1) {
      // ---- [D] publish coalesced bf16 (8B dwordx2 sc0 sc1), per-wave drain+seq ----
      if (l < 16) {
        const int br = wave*4 + (l>>2);                     // local b row
        const int c4 = l & 3;                               // h quad
        f32x4 v = *(const f32x4*)&hxe[br*17 + c4*4];
        unsigned d0 = f2bfu(v[0]) | (f2bfu(v[1]) << 16);
        unsigned d1 = f2bfu(v[2]) | (f2bfu(v[3]) << 16);
        unsigned long long ha =
          (unsigned long long)(hxg + ((size_t)((t+1)&1))*262144
                               + (((size_t)(bgp*BG + br)) << 10) + (nh*16 + c4*4)*2);
        asm volatile("global_store_dwordx2 %0, v[30:31], off sc0 sc1"
                     :: "v"(ha), "{v30}"(d0), "{v31}"(d1) : "memory");
      }
      asm volatile("s_waitcnt vmcnt(0)" ::: "memory");      // wave-local drain
      if (l == 0) {
        unsigned long long sa =
          (unsigned long long)(seqb + (((size_t)bgp*8 + wave)*NH + nh)*4);
        unsigned sv = (unsigned)(t+1);
        asm volatile("global_store_dword %0, %1, off sc0 sc1" :: "v"(sa), "v"(sv) : "memory");
      }
      out[((size_t)t*B_ + b_out)*H_ + h_out] = hxe[eb*17 + hl];   // ys, overlaps poll
      {
        unsigned long long fa =
          (unsigned long long)(seqb + (((size_t)bgp*8 + wave)*NH + (l & 31))*4);
        unsigned v;
        do {
          asm volatile("global_load_dword %0, %1, off sc0 sc1\n\ts_waitcnt vmcnt(0)"
                       : "=v"(v) : "v"(fa) : "memory");
        } while (v < (unsigned)(t+1));
      }
      __syncthreads();                                      // S5: step barrier done
    } else {
      // final step: ys + final hx (coalesced from hxe), then cx via the same tile
      float hv = hxe[eb*17 + hl];
      out[((size_t)t*B_ + b_out)*H_ + h_out] = hv;
      out[(size_t)T_*B_*H_ + (size_t)b_out*H_ + h_out] = hv;
      __syncthreads();
      hxe[eloc*17 + wq*4 + q4] = cxr;
      __syncthreads();
      out[(size_t)T_*B_*H_ + (size_t)B_*H_ + (size_t)b_out*H_ + h_out] = hxe[eb*17 + hl];
    }
  }
}

extern "C" void kernel_launch(void* const* d_in, const int* in_sizes, int n_in,
                              void* d_out, int out_size, void* d_ws, size_t ws_size,
                              hipStream_t stream) {
  const float* x    = (const float*)d_in[0];
  const float* Wf_l = (const float*)d_in[1];  const float* bf_l = (const float*)d_in[2];
  const float* Wf_p = (const float*)d_in[3];  const float* bf_p = (const float*)d_in[4];
  const float* Wf_r = (const float*)d_in[5];
  const float* Wi_l = (const float*)d_in[6];  const float* bi_l = (const float*)d_in[7];
  const float* Wi_p = (const float*)d_in[8];  const float* bi_p = (const float*)d_in[9];
  const float* Wi_r = (const float*)d_in[10];
  const float* Wg_l = (const float*)d_in[11]; const float* bg_l = (const float*)d_in[12];
  const float* Wg_p = (const float*)d_in[13]; const float* bg_p = (const float*)d_in[14];
  const float* Wg_r = (const float*)d_in[15];
  const float* Wo_l = (const float*)d_in[16]; const float* bo_l = (const float*)d_in[17];
  const float* Wo_p = (const float*)d_in[18]; const float* bo_p = (const float*)d_in[19];
  const float* Wo_r = (const float*)d_in[20];
  float* out = (float*)d_out;
  char*  wsb = (char*)d_ws;

  void* args[] = { &x,
                   &Wf_l, &bf_l, &Wf_p, &bf_p, &Wf_r,
                   &Wi_l, &bi_l, &Wi_p, &bi_p, &Wi_r,
                   &Wg_l, &bg_l, &Wg_p, &bg_p, &Wg_r,
                   &Wo_l, &bo_l, &Wo_p, &bo_p, &Wo_r,
                   &out, &wsb };
  hipLaunchCooperativeKernel((void*)qlstm_kernel, dim3(NB*NH), dim3(NTH),
                             args, 0, stream);
}

// Round 7
// 1247.884 us; speedup vs baseline: 2.1782x; 1.2436x over previous
//
#include <hip/hip_runtime.h>
#include <hip/hip_cooperative_groups.h>
#include <math.h>

namespace cg = cooperative_groups;

#define T_ 256
#define B_ 256
#define I_ 256
#define H_ 512
#define NB 8          // batch groups (independent recurrent chains)
#define NH 32         // h-group WGs per batch group
#define BG 32         // batches per group
#define NTH 512

typedef __attribute__((ext_vector_type(8))) short short8;
typedef __attribute__((ext_vector_type(4))) float f32x4;
typedef __attribute__((ext_vector_type(4))) unsigned int uint4v;
typedef unsigned long long ull;

__device__ __forceinline__ float sig_(float v){ return 1.0f/(1.0f+__expf(-v)); }
__device__ __forceinline__ float tanh_(float v){ float e=__expf(2.f*v); return 1.f-2.f/(e+1.f); }
__device__ __forceinline__ unsigned f2bfu(float f){        // fp32 -> bf16 RTNE (low 16)
  unsigned u = __float_as_uint(f);
  return (u + 0x7fffu + ((u>>16)&1u)) >> 16;
}
__device__ __forceinline__ short f2bf(float f){ return (short)f2bfu(f); }
__device__ __forceinline__ bool tagok(uint4v c, unsigned tg){
  return ((c[0]&0xffffu)==tg) & ((c[1]&0xffffu)==tg) &
         ((c[2]&0xffffu)==tg) & ((c[3]&0xffffu)==tg);
}

__global__ __launch_bounds__(NTH)
void qlstm_kernel(
    const float* __restrict__ x,
    const float* __restrict__ Wf_l, const float* __restrict__ bf_l,
    const float* __restrict__ Wf_p, const float* __restrict__ bf_p,
    const float* __restrict__ Wf_r,
    const float* __restrict__ Wi_l, const float* __restrict__ bi_l,
    const float* __restrict__ Wi_p, const float* __restrict__ bi_p,
    const float* __restrict__ Wi_r,
    const float* __restrict__ Wg_l, const float* __restrict__ bg_l,
    const float* __restrict__ Wg_p, const float* __restrict__ bg_p,
    const float* __restrict__ Wg_r,
    const float* __restrict__ Wo_l, const float* __restrict__ bo_l,
    const float* __restrict__ Wo_p, const float* __restrict__ bo_p,
    const float* __restrict__ Wo_r,
    float* __restrict__ out,
    char* __restrict__ wsb)
{
  __shared__ char  hxT[32*1024];        // [32 b][512 k] bf16, XOR-swizzled rows
  __shared__ float hxe[32*17];          // [b][h(+pad)] fp32 transpose tile

  float*    sx   = (float*)wsb;                      // [T][4][B] fp32, 1 MiB
  unsigned* hxgT = (unsigned*)(wsb + (1u<<20));      // [2][B][H] tagged dwords, 1 MiB

  const int tid  = threadIdx.x;
  const int wgid = blockIdx.x;
  const int bgp  = wgid & 7;            // batch group
  const int nh   = wgid >> 3;           // h group 0..31
  const int wave = tid >> 6;
  const int l    = tid & 63;
  const int l15  = l & 15;
  const int q4   = l >> 4;
  const int n    = wave >> 2;           // batch half (0/1)
  const int wq   = wave & 3;            // h quad within the WG's 16 h
  const int wave4 = wave * 4;

  // ---------------- init (once per launch) ----------------
  for (int idx = tid; idx < 8*4*BG; idx += NTH) {
    int g   = idx >> 8;
    int rem = idx & 255;
    int tt  = rem >> 5;
    int b   = rem & 31;
    int t   = nh*8 + tt;
    int bglob = bgp*BG + b;
    const float* wl = (g==0)?Wf_l:(g==1)?Wi_l:(g==2)?Wg_l:Wo_l;
    const float* bl = (g==0)?bf_l:(g==1)?bi_l:(g==2)?bg_l:bo_l;
    const float* xr = x + ((size_t)t*B_ + bglob)*I_;
    float a = 0.f;
    #pragma unroll 8
    for (int i2 = 0; i2 < I_; i2 += 4) {
      float4 v = *(const float4*)(xr + i2);
      a += v.x*wl[i2] + v.y*wl[i2+1] + v.z*wl[i2+2] + v.w*wl[i2+3];
    }
    sx[((size_t)t*4 + g)*B_ + bglob] = a + bl[0];
  }
  // zero this WG's tag region in BOTH parity buffers (replay-safe)
  if (tid < 256) {
    const int pb = tid >> 3, seg = tid & 7;
    ull z = 0;
    ull pa0 = (ull)(hxgT + (size_t)(bgp*BG + pb)*H_ + nh*16 + seg*2);
    ull pa1 = pa0 + (size_t)(B_*H_)*4;
    asm volatile("global_store_dwordx2 %0, %1, off sc0 sc1" :: "v"(pa0), "v"(z) : "memory");
    asm volatile("global_store_dwordx2 %0, %1, off sc0 sc1" :: "v"(pa1), "v"(z) : "memory");
  }

  // A-fragments, gate-interleaved rows: tile row r -> (hloc = r>>2, gate = r&3)
  // q-tile rows replicated: row r -> gate r&3 (all 4 q-dots reach every lane)
  short8 afrag[16];
  short8 afragq[16];
  {
    const int g  = l15 & 3;
    const float* wr = (g==0)?Wf_r:(g==1)?Wi_r:(g==2)?Wg_r:Wo_r;
    const float* wl = (g==0)?Wf_l:(g==1)?Wi_l:(g==2)?Wg_l:Wo_l;
    const int hA = nh*16 + wq*4 + (l15>>2);
    #pragma unroll
    for (int kk = 0; kk < 16; ++kk) {
      const float* srcA = wr + (size_t)hA*H_ + kk*32 + q4*8;
      const float* srcQ = wl + I_ + kk*32 + q4*8;
      short8 pa, pq;
      #pragma unroll
      for (int j = 0; j < 8; ++j) { pa[j] = f2bf(srcA[j]); pq[j] = f2bf(srcQ[j]); }
      afrag[kk]  = pa;
      afragq[kk] = pq;
    }
  }

  // lane-local epilogue ownership: b = bgp*32 + n*16 + l15, h = nh*16 + wq*4 + q4
  const int h_ep = nh*16 + wq*4 + q4;
  const int b_ep = bgp*BG + n*16 + l15;
  const int eloc = n*16 + l15;
  const float wfp = Wf_p[h_ep], bfp = bf_p[h_ep];
  const float wip = Wi_p[h_ep], bip = bi_p[h_ep];
  const float wgp = Wg_p[h_ep], bgw = bg_p[h_ep];
  const float wop = Wo_p[h_ep], bop = bo_p[h_ep];
  float cxr = 0.f;

  // coalesced-output ownership: eb = tid>>4 (b row), hl = tid&15 (h)
  const int hl = tid & 15;
  const int eb = tid >> 4;
  const int h_out = nh*16 + hl;
  const int b_out = bgp*BG + eb;

  asm volatile("s_waitcnt vmcnt(0)" ::: "memory");
  cg::grid_group grid = cg::this_grid();
  grid.sync();                          // publishes sx + tag zeros device-wide

  const int brow = eloc * 1024;
  const int bsw  = (eloc & 7) << 4;
  const int bq16 = q4 * 16;

  for (int t = 0; t < T_; ++t) {
    const float sx0 = sx[((size_t)t*4+0)*B_ + b_ep];
    const float sx1 = sx[((size_t)t*4+1)*B_ + b_ep];
    const float sx2 = sx[((size_t)t*4+2)*B_ + b_ep];
    const float sx3 = sx[((size_t)t*4+3)*B_ + b_ep];

    if (t == 0) {
      #pragma unroll
      for (int i = 0; i < 4; ++i)
        *(f32x4*)(hxT + ((wave4+i)*1024 + 16*l)) = (f32x4){0.f,0.f,0.f,0.f};
    } else {
      // ---- stage hx(t): poll tagged dwords from the exchange buffer (LLC) ----
      const unsigned* bb = hxgT + (size_t)(t&1)*(B_*H_)
                           + (size_t)(bgp*BG + wave4)*H_ + l*4;
      ull a0 = (ull)(bb);
      ull a1 = (ull)(bb + 256);
      ull a2 = (ull)(bb + H_);
      ull a3 = (ull)(bb + H_ + 256);
      ull a4 = (ull)(bb + 2*H_);
      ull a5 = (ull)(bb + 2*H_ + 256);
      ull a6 = (ull)(bb + 3*H_);
      ull a7 = (ull)(bb + 3*H_ + 256);
      const unsigned tg = (unsigned)t;
      uint4v c0,c1,c2,c3,c4,c5,c6,c7;
      bool ok;
      do {
        asm volatile("global_load_dwordx4 %0, %1, off sc0 sc1" : "=v"(c0) : "v"(a0) : "memory");
        asm volatile("global_load_dwordx4 %0, %1, off sc0 sc1" : "=v"(c1) : "v"(a1) : "memory");
        asm volatile("global_load_dwordx4 %0, %1, off sc0 sc1" : "=v"(c2) : "v"(a2) : "memory");
        asm volatile("global_load_dwordx4 %0, %1, off sc0 sc1" : "=v"(c3) : "v"(a3) : "memory");
        asm volatile("global_load_dwordx4 %0, %1, off sc0 sc1" : "=v"(c4) : "v"(a4) : "memory");
        asm volatile("global_load_dwordx4 %0, %1, off sc0 sc1" : "=v"(c5) : "v"(a5) : "memory");
        asm volatile("global_load_dwordx4 %0, %1, off sc0 sc1" : "=v"(c6) : "v"(a6) : "memory");
        asm volatile("global_load_dwordx4 %0, %1, off sc0 sc1" : "=v"(c7) : "v"(a7) : "memory");
        asm volatile("s_waitcnt vmcnt(0)" ::: "memory");
        ok = tagok(c0,tg) & tagok(c1,tg) & tagok(c2,tg) & tagok(c3,tg)
           & tagok(c4,tg) & tagok(c5,tg) & tagok(c6,tg) & tagok(c7,tg);
        if (!ok) __builtin_amdgcn_s_sleep(2);
      } while (!ok);

      // unpack: high 16 bits of each dword are the bf16 payload
      #define EMIT_CH(j, half, cq)                                              \
        { const int rr = wave4 + (j);                                           \
          unsigned d0 = (cq[0]>>16) | (cq[1] & 0xffff0000u);                    \
          unsigned d1 = (cq[2]>>16) | (cq[3] & 0xffff0000u);                    \
          const int off = (((half)*512 + 8*l) ^ ((rr&7)<<4));                   \
          *(ull*)(hxT + rr*1024 + off) = (ull)d0 | ((ull)d1<<32); }
      EMIT_CH(0, 0, c0); EMIT_CH(0, 1, c1);
      EMIT_CH(1, 0, c2); EMIT_CH(1, 1, c3);
      EMIT_CH(2, 0, c4); EMIT_CH(2, 1, c5);
      EMIT_CH(3, 0, c6); EMIT_CH(3, 1, c7);
      #undef EMIT_CH

      out[((size_t)(t-1)*B_ + b_out)*H_ + h_out] = hxe[eb*17 + hl];  // ys[t-1]
    }
    __syncthreads();                                        // S1: tile ready

    // ---- MFMA K-loop: main (gate-interleaved) + q (replicated) ----
    f32x4 acc  = {0.f,0.f,0.f,0.f};
    f32x4 accq = {0.f,0.f,0.f,0.f};
    #pragma unroll
    for (int kk = 0; kk < 16; ++kk) {
      short8 bf = *(const short8*)(hxT + brow + ((kk*64 + bq16) ^ bsw));
      acc  = __builtin_amdgcn_mfma_f32_16x16x32_bf16(afrag[kk],  bf, acc,  0, 0, 0);
      accq = __builtin_amdgcn_mfma_f32_16x16x32_bf16(afragq[kk], bf, accq, 0, 0, 0);
    }

    // ---- epilogue: lane-local gates -> hnew -> transpose tile ----
    {
      float q0 = __cosf(sx0 + accq[0]);
      float q1 = __cosf(sx1 + accq[1]);
      float q2 = __cosf(sx2 + accq[2]);
      float q3 = __cosf(sx3 + accq[3]);
      float fv = sig_ (q0*wfp + bfp) + acc[0];
      float iv = sig_ (q1*wip + bip) + acc[1];
      float gv = tanh_(q2*wgp + bgw) + acc[2];
      float ov = sig_ (q3*wop + bop) + acc[3];
      cxr = fv*cxr + iv*gv;
      float hnew = ov * tanh_(cxr);
      hxe[eloc*17 + wq*4 + q4] = hnew;
    }
    __syncthreads();                                        // S3: hxe ready

    if (t < T_-1) {
      // ---- publish: coalesced tagged dwordx2 (LLC write-through), no drain ----
      if (tid < 256) {
        const int pb = tid >> 3, seg = tid & 7;
        float v0 = hxe[pb*17 + seg*2], v1 = hxe[pb*17 + seg*2 + 1];
        unsigned tn = (unsigned)(t+1);
        unsigned d0 = (f2bfu(v0)<<16) | tn, d1 = (f2bfu(v1)<<16) | tn;
        ull val = (ull)d0 | ((ull)d1<<32);
        ull pa = (ull)(hxgT + (size_t)((t+1)&1)*(B_*H_)
                       + (size_t)(bgp*BG + pb)*H_ + nh*16 + seg*2);
        asm volatile("global_store_dwordx2 %0, %1, off sc0 sc1" :: "v"(pa), "v"(val) : "memory");
      }
      // tags self-synchronize the consumers: no drain, no flags, no join
    }
  }

  // ---- tail: ys[T-1], final hx, final cx (coalesced via hxe) ----
  {
    float hv = hxe[eb*17 + hl];
    out[((size_t)(T_-1)*B_ + b_out)*H_ + h_out] = hv;
    out[(size_t)T_*B_*H_ + (size_t)b_out*H_ + h_out] = hv;
    __syncthreads();
    hxe[eloc*17 + wq*4 + q4] = cxr;
    __syncthreads();
    out[(size_t)T_*B_*H_ + (size_t)(B_*H_) + (size_t)b_out*H_ + h_out] = hxe[eb*17 + hl];
  }
}

extern "C" void kernel_launch(void* const* d_in, const int* in_sizes, int n_in,
                              void* d_out, int out_size, void* d_ws, size_t ws_size,
                              hipStream_t stream) {
  const float* x    = (const float*)d_in[0];
  const float* Wf_l = (const float*)d_in[1];  const float* bf_l = (const float*)d_in[2];
  const float* Wf_p = (const float*)d_in[3];  const float* bf_p = (const float*)d_in[4];
  const float* Wf_r = (const float*)d_in[5];
  const float* Wi_l = (const float*)d_in[6];  const float* bi_l = (const float*)d_in[7];
  const float* Wi_p = (const float*)d_in[8];  const float* bi_p = (const float*)d_in[9];
  const float* Wi_r = (const float*)d_in[10];
  const float* Wg_l = (const float*)d_in[11]; const float* bg_l = (const float*)d_in[12];
  const float* Wg_p = (const float*)d_in[13]; const float* bg_p = (const float*)d_in[14];
  const float* Wg_r = (const float*)d_in[15];
  const float* Wo_l = (const float*)d_in[16]; const float* bo_l = (const float*)d_in[17];
  const float* Wo_p = (const float*)d_in[18]; const float* bo_p = (const float*)d_in[19];
  const float* Wo_r = (const float*)d_in[20];
  float* out = (float*)d_out;
  char*  wsb = (char*)d_ws;

  void* args[] = { &x,
                   &Wf_l, &bf_l, &Wf_p, &bf_p, &Wf_r,
                   &Wi_l, &bi_l, &Wi_p, &bi_p, &Wi_r,
                   &Wg_l, &bg_l, &Wg_p, &bg_p, &Wg_r,
                   &Wo_l, &bo_l, &Wo_p, &bo_p, &Wo_r,
                   &out, &wsb };
  hipLaunchCooperativeKernel((void*)qlstm_kernel, dim3(NB*NH), dim3(NTH),
                             args, 0, stream);
}